// Round 5
// baseline (300.795 us; speedup 1.0000x reference)
//
#include <hip/hip_runtime.h>

typedef float f2 __attribute__((ext_vector_type(2)));

#define IMG 512
#define TW 32
#define TH 32
#define NG 12            // float4 col-groups per tile row: 48 cols = 32 out + 8 halo each side
#define SROW 148         // LDS row stride in dwords: 96 A(f2 fp32) + 48 B(packed 2xfp16) + 4 pad
                         //   -> 592 B/row; quad count 37 (ODD: full bank-quad permutation over rows)
#define BOFFD 96         // B-part offset within a row, in dwords (384 B, 16B-aligned)
#define N_TOT (16 * 3 * 512 * 512)
#define NBLK (256 * 48)  // total blocks of ssim_main
#define NSLOT 1024       // fallback atomic slots

// Gaussian(win=11, sigma=1.5), normalized, pre-doubled (SGPR-pair broadcast for pk ops).
__device__ __constant__ f2 Gw2[11] = {
    {0.00102838f, 0.00102838f}, {0.00759876f, 0.00759876f},
    {0.03600077f, 0.03600077f}, {0.10936086f, 0.10936086f},
    {0.21300537f, 0.21300537f}, {0.26601173f, 0.26601173f},
    {0.21300537f, 0.21300537f}, {0.10936086f, 0.10936086f},
    {0.03600077f, 0.03600077f}, {0.00759876f, 0.00759876f},
    {0.00102838f, 0.00102838f}};

// fp16 pack/unpack as pure-u32 inline asm (no _Float16 C-type in this TU).
__device__ __forceinline__ unsigned pkh(float a, float b) {   // (a,b) -> lo16/hi16 fp16 RTZ
    unsigned r;
    asm("v_cvt_pkrtz_f16_f32 %0, %1, %2" : "=v"(r) : "v"(a), "v"(b));
    return r;
}
__device__ __forceinline__ f2 uph(unsigned u) {               // lo16/hi16 fp16 -> (f32,f32)
    float lo, hi;
    const unsigned uh = u >> 16;
    asm("v_cvt_f32_f16 %0, %1" : "=v"(lo) : "v"(u));
    asm("v_cvt_f32_f16 %0, %1" : "=v"(hi) : "v"(uh));
    return (f2){lo, hi};
}

// Packed vertical taps for a row-pair from one input row k.
__device__ __forceinline__ void vtaps(const float4 P, const float4 T, const int k,
                                      f2 A0[4][2], f2 A1[4][2]) {
    const f2 p[2] = {{P.x, P.y}, {P.z, P.w}};
    const f2 t[2] = {{T.x, T.y}, {T.z, T.w}};
#pragma unroll
    for (int h = 0; h < 2; ++h) {
        const f2 ss = p[h] * p[h] + t[h] * t[h];
        const f2 pt = p[h] * t[h];
        if (k < 11) {                              // tap k for row r0
            const f2 w = Gw2[k];
            A0[0][h] += w * p[h];
            A0[1][h] += w * t[h];
            A0[2][h] += w * ss;
            A0[3][h] += w * pt;
        }
        if (k > 0) {                               // tap k-1 for row r0+1
            const f2 w = Gw2[k - 1];
            A1[0][h] += w * p[h];
            A1[1][h] += w * t[h];
            A1[2][h] += w * ss;
            A1[3][h] += w * pt;
        }
    }
}

// OCCUPANCY/REGALLOC PIN (round-4 post-mortem): with __launch_bounds__(256,8) and an
// LDS footprint that ALLOWS 8 waves/EU (19456 B), LLVM's waves-per-eu range {8,+inf}
// let the scheduler target 16 waves/EU (VGPR 32!) and spill ~64 B/thread to scratch
// (WRITE_SIZE 210 MB, 2x regression) -- an occupancy the LDS cap makes unreachable.
// Round 0 (26624 B LDS -> max 6 waves/EU < min 8) never triggered it: unsatisfiable
// range fell back to relaxed allocation (VGPR 60). Fix: pin waves_per_eu(8,8) so the
// VGPR budget is exactly 512/8 = 64, no incentive to spill below it.
// Also NEVER: runtime-index register arrays; hand-pipeline the phase-1 k-loop.
__global__ __attribute__((amdgpu_flat_work_group_size(256, 256)))
__attribute__((amdgpu_waves_per_eu(8, 8)))
void ssim_main(const float* __restrict__ pred,
               const float* __restrict__ tgt,
               float* __restrict__ ws,
               int parts_mode) {
    // Unified vertically-blurred plane, 32 rows x (48 A-cols fp32 | 48 B-cols packed fp16x2).
    //   A(row,c) = (vblur p, vblur t)              f2  at dword row*SROW + 2c
    //   B(row,c) = pkrtz(vblur p^2+t^2, vblur p*t) u32 at dword row*SROW + BOFFD + c
    // 32*148*4 = 18944 B -> 19456 alloc -> 8 blocks/CU (rounds 1-4 measured Occupancy 55-63
    // even while spilling; numerics harness-verified absmax 0.0 in rounds 1-4).
    __shared__ __align__(16) float plane[TH * SROW];
    __shared__ float red[4];

    const int tid = threadIdx.x;
    const int tile = blockIdx.x;             // 16x16 tiles of 32x32
    const int plane_id = blockIdx.y;         // 48 planes
    const int tile_x = tile & 15;
    const int tile_y = tile >> 4;
    const int tx = tile_x * TW;
    const int ty = tile_y * TH;
    const float* pbase = pred + (size_t)plane_id * (IMG * IMG);
    const float* tbase = tgt + (size_t)plane_id * (IMG * IMG);

    // ---- Phase 1: vertical 11-tap blur straight from global, row-pair per task ----
    if (tid < NG * 16) {
        const int g4 = tid % NG;             // col group
        const int rp = tid / NG;             // row pair
        const int r0 = rp * 2;               // local output row
        const int col = tx - 8 + (g4 << 2);  // global col of float4 (16B-aligned)
        const int ybase = ty + r0 - 5;

        f2 A0[4][2], A1[4][2];
#pragma unroll
        for (int q = 0; q < 4; ++q)
#pragma unroll
            for (int h = 0; h < 2; ++h) { A0[q][h] = (f2)0.f; A1[q][h] = (f2)0.f; }

        // Block-uniform branch (scalar, no divergence); loads plain, compiler-scheduled.
        if ((unsigned)(tile_x - 1) < 14u && (unsigned)(tile_y - 1) < 14u) {
            const float* pp = pbase + (ybase * IMG + col);
            const float* tp = tbase + (ybase * IMG + col);
#pragma unroll
            for (int k = 0; k < 12; ++k) {
                const float4 P = *(const float4*)(pp + k * IMG);
                const float4 T = *(const float4*)(tp + k * IMG);
                vtaps(P, T, k, A0, A1);
            }
        } else {
            const bool xin = (unsigned)col < (unsigned)IMG;  // all-in or all-out
#pragma unroll
            for (int k = 0; k < 12; ++k) {
                const int y = ybase + k;
                float4 P = make_float4(0.f, 0.f, 0.f, 0.f);
                float4 T = make_float4(0.f, 0.f, 0.f, 0.f);
                if (xin && (unsigned)y < (unsigned)IMG) {
                    const int gidx = y * IMG + col;
                    P = *(const float4*)(pbase + gidx);
                    T = *(const float4*)(tbase + gidx);
                }
                vtaps(P, T, k, A0, A1);
            }
        }

        // Transpose in registers -> b128 stores. r is a compile-time unroll var.
        const int cb = g4 << 2;              // pixel col base (col 0 == global tx-8)
#pragma unroll
        for (int r = 0; r < 2; ++r) {
            f2 (*A)[2] = r ? A1 : A0;
            float* rowA = &plane[(r0 + r) * SROW + (cb << 1)];
            *(float4*)rowA       = make_float4(A[0][0].x, A[1][0].x, A[0][0].y, A[1][0].y);
            *(float4*)(rowA + 4) = make_float4(A[0][1].x, A[1][1].x, A[0][1].y, A[1][1].y);
            // B: 4 pixels packed fp16x2(ss,pt) = one uint4 = one ds_write_b128.
            uint4 bv;
            bv.x = pkh(A[2][0].x, A[3][0].x);
            bv.y = pkh(A[2][0].y, A[3][0].y);
            bv.z = pkh(A[2][1].x, A[3][1].x);
            bv.w = pkh(A[2][1].y, A[3][1].y);
            *(uint4*)&plane[(r0 + r) * SROW + BOFFD + cb] = bv;
        }
    }
    __syncthreads();

    // ---- Phase 2: packed horizontal 11-tap blur + SSIM map, 4 outputs per thread ----
    // SCATTER form: each loaded pixel is consumed immediately into the <=4 outputs it
    // feeds. Peak live ~30 dwords.
    float lsum = 0.f;
    {
        const int oy = tid >> 3;             // 32 rows
        const int ox = (tid & 7) << 2;       // 8 groups of 4 output cols
        const float* rowbase = &plane[oy * SROW];

        f2 acc[4];                           // (mu1, mu2) per j
        f2 sacc[4];                          // (bss, bpt) per j
#pragma unroll
        for (int j = 0; j < 4; ++j) { acc[j] = (f2)0.f; sacc[j] = (f2)0.f; }

        // A part: load f2 cols ox+2..ox+17 (8 x b128, 16B-aligned). Pixel index i
        // (col ox+2+i) feeds output j with weight Gw2[i-1-j] when 0<=i-1-j<=10.
        {
            const float4* rowA = (const float4*)(rowbase + ((ox + 2) << 1));
#pragma unroll
            for (int i4 = 0; i4 < 8; ++i4) {
                const float4 q = rowA[i4];
                const f2 v[2] = {{q.x, q.y}, {q.z, q.w}};
#pragma unroll
                for (int h = 0; h < 2; ++h) {
                    const int i = 2 * i4 + h;
#pragma unroll
                    for (int j = 0; j < 4; ++j) {
                        const int k = i - 1 - j;
                        if (k >= 0 && k <= 10) acc[j] += Gw2[k] * v[h];
                    }
                }
            }
        }

        // B part: load packed pixels ox..ox+19 (5 x b128, contiguous span). Pixel
        // offset m (col ox+m) feeds output j with weight Gw2[m-3-j] when 0<=m-3-j<=10.
        {
            const uint4* rowB = (const uint4*)(rowbase + BOFFD + ox);
#pragma unroll
            for (int i4 = 0; i4 < 5; ++i4) {
                const uint4 q = rowB[i4];
                const unsigned qq[4] = {q.x, q.y, q.z, q.w};
#pragma unroll
                for (int c = 0; c < 4; ++c) {
                    const int m = 4 * i4 + c;
                    if (m >= 3 && m <= 16) {
                        const f2 v = uph(qq[c]);
#pragma unroll
                        for (int j = 0; j < 4; ++j) {
                            const int k = m - 3 - j;
                            if (k >= 0 && k <= 10) sacc[j] += Gw2[k] * v;
                        }
                    }
                }
            }
        }

        const float C1 = 0.0001f;            // 0.01^2
        const float C2 = 0.0009f;            // 0.03^2
#pragma unroll
        for (int j = 0; j < 4; ++j) {
            const float m1 = acc[j].x, m2 = acc[j].y;
            const float bss = sacc[j].x, bpt = sacc[j].y;
            const float mu1s = m1 * m1;
            const float mu2s = m2 * m2;
            const float mu12 = m1 * m2;
            const float A = mu1s + mu2s;
            const float s12 = bpt - mu12;    // sigma12
            const float sden = bss - A;      // sigma1^2 + sigma2^2
            const float num = fmaf(2.f, mu12, C1) * fmaf(2.f, s12, C2);
            const float den = (A + C1) * (sden + C2);
            lsum += num * __builtin_amdgcn_rcpf(den);   // rcp err ~1e-7 << 1.98e-2 threshold
        }
    }

    // ---- Reduction: wave shuffle -> LDS -> one plain store per block ----
#pragma unroll
    for (int off = 32; off > 0; off >>= 1) lsum += __shfl_down(lsum, off, 64);
    if ((tid & 63) == 0) red[tid >> 6] = lsum;
    __syncthreads();
    if (tid == 0) {
        const float bs = (red[0] + red[1]) + (red[2] + red[3]);
        const int bid = blockIdx.y * gridDim.x + blockIdx.x;
        if (parts_mode) {
            ws[bid] = bs;                    // contention-free
        } else {
            atomicAdd(&ws[bid & (NSLOT - 1)], bs);  // fallback: shallow contention
        }
    }
}

// Sum `count4` float4 partials from ws, write 1 - sum/N.
__global__ __launch_bounds__(1024) void ssim_final(const float4* __restrict__ ws4,
                                                   float* __restrict__ out, int count4) {
    __shared__ float red[16];
    const int tid = threadIdx.x;
    float s = 0.f;
    for (int i = tid; i < count4; i += 1024) {
        const float4 w = ws4[i];
        s += (w.x + w.y) + (w.z + w.w);
    }
#pragma unroll
    for (int off = 32; off > 0; off >>= 1) s += __shfl_down(s, off, 64);
    if ((tid & 63) == 0) red[tid >> 6] = s;
    __syncthreads();
    if (tid == 0) {
        float tot = 0.f;
#pragma unroll
        for (int i = 0; i < 16; ++i) tot += red[i];
        out[0] = 1.0f - tot * (1.0f / (float)N_TOT);
    }
}

extern "C" void kernel_launch(void* const* d_in, const int* in_sizes, int n_in,
                              void* d_out, int out_size, void* d_ws, size_t ws_size,
                              hipStream_t stream) {
    const float* pred = (const float*)d_in[0];
    const float* tgt = (const float*)d_in[1];
    float* out = (float*)d_out;
    float* ws = (float*)d_ws;

    const int parts_mode = (ws_size >= (size_t)NBLK * sizeof(float)) ? 1 : 0;
    if (!parts_mode) {
        hipMemsetAsync(ws, 0, NSLOT * sizeof(float), stream);
    }
    dim3 grid(256, 48);  // 16x16 tiles x (16*3) planes
    ssim_main<<<grid, 256, 0, stream>>>(pred, tgt, ws, parts_mode);
    ssim_final<<<1, 1024, 0, stream>>>((const float4*)ws, out,
                                       (parts_mode ? NBLK : NSLOT) / 4);
}

// Round 6
// 166.404 us; speedup vs baseline: 1.8076x; 1.8076x over previous
//
#include <hip/hip_runtime.h>

typedef float f2 __attribute__((ext_vector_type(2)));

#define IMG 512
#define TW 32
#define TH 32
#define NG 12            // float4 col-groups per tile row: 48 cols = 32 out + 8 halo each side
#define SROW 148         // LDS row stride in dwords: 96 A(f2 fp32) + 48 B(packed 2xfp16) + 4 pad
                         //   -> 592 B/row; quad count 37 (ODD: full bank-quad permutation over rows)
#define BOFFD 96         // B-part offset within a row, in dwords (384 B, 16B-aligned)
#define N_TOT (16 * 3 * 512 * 512)
#define NBLK (256 * 48)  // total blocks of ssim_main
#define NSLOT 1024       // fallback atomic slots

// Gaussian(win=11, sigma=1.5), normalized, pre-doubled (SGPR-pair broadcast for pk ops).
__device__ __constant__ f2 Gw2[11] = {
    {0.00102838f, 0.00102838f}, {0.00759876f, 0.00759876f},
    {0.03600077f, 0.03600077f}, {0.10936086f, 0.10936086f},
    {0.21300537f, 0.21300537f}, {0.26601173f, 0.26601173f},
    {0.21300537f, 0.21300537f}, {0.10936086f, 0.10936086f},
    {0.03600077f, 0.03600077f}, {0.00759876f, 0.00759876f},
    {0.00102838f, 0.00102838f}};

// fp16 pack/unpack as pure-u32 inline asm (no _Float16 C-type in this TU).
// Numerics harness-verified absmax 0.0 in rounds 1-5.
__device__ __forceinline__ unsigned pkh(float a, float b) {   // (a,b) -> lo16/hi16 fp16 RTZ
    unsigned r;
    asm("v_cvt_pkrtz_f16_f32 %0, %1, %2" : "=v"(r) : "v"(a), "v"(b));
    return r;
}
__device__ __forceinline__ f2 uph(unsigned u) {               // lo16/hi16 fp16 -> (f32,f32)
    float lo, hi;
    const unsigned uh = u >> 16;
    asm("v_cvt_f32_f16 %0, %1" : "=v"(lo) : "v"(u));
    asm("v_cvt_f32_f16 %0, %1" : "=v"(hi) : "v"(uh));
    return (f2){lo, hi};
}

// Packed vertical taps for a row-pair from one input row k.
__device__ __forceinline__ void vtaps(const float4 P, const float4 T, const int k,
                                      f2 A0[4][2], f2 A1[4][2]) {
    const f2 p[2] = {{P.x, P.y}, {P.z, P.w}};
    const f2 t[2] = {{T.x, T.y}, {T.z, T.w}};
#pragma unroll
    for (int h = 0; h < 2; ++h) {
        const f2 ss = p[h] * p[h] + t[h] * t[h];
        const f2 pt = p[h] * t[h];
        if (k < 11) {                              // tap k for row r0
            const f2 w = Gw2[k];
            A0[0][h] += w * p[h];
            A0[1][h] += w * t[h];
            A0[2][h] += w * ss;
            A0[3][h] += w * pt;
        }
        if (k > 0) {                               // tap k-1 for row r0+1
            const f2 w = Gw2[k - 1];
            A1[0][h] += w * p[h];
            A1[1][h] += w * t[h];
            A1[2][h] += w * ss;
            A1[3][h] += w * pt;
        }
    }
}

// LAUNCH-BOUNDS LAW (7-data-point post-mortem, rounds 0-5 + prev session):
// gfx950 budgets ARCH-VGPRs = 256/min_waves_per_eu (half of the unified 512 file):
//   (256,5)->cap 51 (saw 48, spill)   (256,6)->cap 42 (saw 40, spill)
//   (256,8)+LDS 19456 (8/EU achievable)->cap 32 -> catastrophic spill (rounds 1-5)
//   (256,8)+LDS 26624 (8/EU UNachievable)->constraint dropped -> 60, clean (round 0)
// Therefore: (256,4) -> cap 64 >= the ~60 this kernel needs -> no spill, and
// occupancy is LDS-capped (19456 B -> 6-8 blocks/CU) independent of the bound.
// NEVER raise min_waves above 4 with this LDS. NEVER runtime-index register
// arrays. NEVER hand-pipeline the phase-1 k-loop.
__global__ __launch_bounds__(256, 4) void ssim_main(const float* __restrict__ pred,
                                                    const float* __restrict__ tgt,
                                                    float* __restrict__ ws,
                                                    int parts_mode) {
    // Unified vertically-blurred plane, 32 rows x (48 A-cols fp32 | 48 B-cols packed fp16x2).
    //   A(row,c) = (vblur p, vblur t)              f2  at dword row*SROW + 2c
    //   B(row,c) = pkrtz(vblur p^2+t^2, vblur p*t) u32 at dword row*SROW + BOFFD + c
    // 32*148*4 = 18944 B -> 19456 alloc -> 6-8 blocks/CU.
    __shared__ __align__(16) float plane[TH * SROW];
    __shared__ float red[4];

    const int tid = threadIdx.x;
    const int tile = blockIdx.x;             // 16x16 tiles of 32x32
    const int plane_id = blockIdx.y;         // 48 planes
    const int tile_x = tile & 15;
    const int tile_y = tile >> 4;
    const int tx = tile_x * TW;
    const int ty = tile_y * TH;
    const float* pbase = pred + (size_t)plane_id * (IMG * IMG);
    const float* tbase = tgt + (size_t)plane_id * (IMG * IMG);

    // ---- Phase 1: vertical 11-tap blur straight from global, row-pair per task ----
    if (tid < NG * 16) {
        const int g4 = tid % NG;             // col group
        const int rp = tid / NG;             // row pair
        const int r0 = rp * 2;               // local output row
        const int col = tx - 8 + (g4 << 2);  // global col of float4 (16B-aligned)
        const int ybase = ty + r0 - 5;

        f2 A0[4][2], A1[4][2];
#pragma unroll
        for (int q = 0; q < 4; ++q)
#pragma unroll
            for (int h = 0; h < 2; ++h) { A0[q][h] = (f2)0.f; A1[q][h] = (f2)0.f; }

        // Block-uniform branch (scalar, no divergence); loads plain, compiler-scheduled.
        if ((unsigned)(tile_x - 1) < 14u && (unsigned)(tile_y - 1) < 14u) {
            const float* pp = pbase + (ybase * IMG + col);
            const float* tp = tbase + (ybase * IMG + col);
#pragma unroll
            for (int k = 0; k < 12; ++k) {
                const float4 P = *(const float4*)(pp + k * IMG);
                const float4 T = *(const float4*)(tp + k * IMG);
                vtaps(P, T, k, A0, A1);
            }
        } else {
            const bool xin = (unsigned)col < (unsigned)IMG;  // all-in or all-out
#pragma unroll
            for (int k = 0; k < 12; ++k) {
                const int y = ybase + k;
                float4 P = make_float4(0.f, 0.f, 0.f, 0.f);
                float4 T = make_float4(0.f, 0.f, 0.f, 0.f);
                if (xin && (unsigned)y < (unsigned)IMG) {
                    const int gidx = y * IMG + col;
                    P = *(const float4*)(pbase + gidx);
                    T = *(const float4*)(tbase + gidx);
                }
                vtaps(P, T, k, A0, A1);
            }
        }

        // Transpose in registers -> b128 stores. r is a compile-time unroll var.
        const int cb = g4 << 2;              // pixel col base (col 0 == global tx-8)
#pragma unroll
        for (int r = 0; r < 2; ++r) {
            f2 (*A)[2] = r ? A1 : A0;
            float* rowA = &plane[(r0 + r) * SROW + (cb << 1)];
            *(float4*)rowA       = make_float4(A[0][0].x, A[1][0].x, A[0][0].y, A[1][0].y);
            *(float4*)(rowA + 4) = make_float4(A[0][1].x, A[1][1].x, A[0][1].y, A[1][1].y);
            // B: 4 pixels packed fp16x2(ss,pt) = one uint4 = one ds_write_b128.
            uint4 bv;
            bv.x = pkh(A[2][0].x, A[3][0].x);
            bv.y = pkh(A[2][0].y, A[3][0].y);
            bv.z = pkh(A[2][1].x, A[3][1].x);
            bv.w = pkh(A[2][1].y, A[3][1].y);
            *(uint4*)&plane[(r0 + r) * SROW + BOFFD + cb] = bv;
        }
    }
    __syncthreads();

    // ---- Phase 2: packed horizontal 11-tap blur + SSIM map, 4 outputs per thread ----
    // SCATTER form: each loaded pixel is consumed immediately into the <=4 outputs it
    // feeds. Peak live ~30 dwords.
    float lsum = 0.f;
    {
        const int oy = tid >> 3;             // 32 rows
        const int ox = (tid & 7) << 2;       // 8 groups of 4 output cols
        const float* rowbase = &plane[oy * SROW];

        f2 acc[4];                           // (mu1, mu2) per j
        f2 sacc[4];                          // (bss, bpt) per j
#pragma unroll
        for (int j = 0; j < 4; ++j) { acc[j] = (f2)0.f; sacc[j] = (f2)0.f; }

        // A part: load f2 cols ox+2..ox+17 (8 x b128, 16B-aligned). Pixel index i
        // (col ox+2+i) feeds output j with weight Gw2[i-1-j] when 0<=i-1-j<=10.
        {
            const float4* rowA = (const float4*)(rowbase + ((ox + 2) << 1));
#pragma unroll
            for (int i4 = 0; i4 < 8; ++i4) {
                const float4 q = rowA[i4];
                const f2 v[2] = {{q.x, q.y}, {q.z, q.w}};
#pragma unroll
                for (int h = 0; h < 2; ++h) {
                    const int i = 2 * i4 + h;
#pragma unroll
                    for (int j = 0; j < 4; ++j) {
                        const int k = i - 1 - j;
                        if (k >= 0 && k <= 10) acc[j] += Gw2[k] * v[h];
                    }
                }
            }
        }

        // B part: load packed pixels ox..ox+19 (5 x b128, contiguous span). Pixel
        // offset m (col ox+m) feeds output j with weight Gw2[m-3-j] when 0<=m-3-j<=10.
        {
            const uint4* rowB = (const uint4*)(rowbase + BOFFD + ox);
#pragma unroll
            for (int i4 = 0; i4 < 5; ++i4) {
                const uint4 q = rowB[i4];
                const unsigned qq[4] = {q.x, q.y, q.z, q.w};
#pragma unroll
                for (int c = 0; c < 4; ++c) {
                    const int m = 4 * i4 + c;
                    if (m >= 3 && m <= 16) {
                        const f2 v = uph(qq[c]);
#pragma unroll
                        for (int j = 0; j < 4; ++j) {
                            const int k = m - 3 - j;
                            if (k >= 0 && k <= 10) sacc[j] += Gw2[k] * v;
                        }
                    }
                }
            }
        }

        const float C1 = 0.0001f;            // 0.01^2
        const float C2 = 0.0009f;            // 0.03^2
#pragma unroll
        for (int j = 0; j < 4; ++j) {
            const float m1 = acc[j].x, m2 = acc[j].y;
            const float bss = sacc[j].x, bpt = sacc[j].y;
            const float mu1s = m1 * m1;
            const float mu2s = m2 * m2;
            const float mu12 = m1 * m2;
            const float A = mu1s + mu2s;
            const float s12 = bpt - mu12;    // sigma12
            const float sden = bss - A;      // sigma1^2 + sigma2^2
            const float num = fmaf(2.f, mu12, C1) * fmaf(2.f, s12, C2);
            const float den = (A + C1) * (sden + C2);
            lsum += num * __builtin_amdgcn_rcpf(den);   // rcp err ~1e-7 << 1.98e-2 threshold
        }
    }

    // ---- Reduction: wave shuffle -> LDS -> one plain store per block ----
#pragma unroll
    for (int off = 32; off > 0; off >>= 1) lsum += __shfl_down(lsum, off, 64);
    if ((tid & 63) == 0) red[tid >> 6] = lsum;
    __syncthreads();
    if (tid == 0) {
        const float bs = (red[0] + red[1]) + (red[2] + red[3]);
        const int bid = blockIdx.y * gridDim.x + blockIdx.x;
        if (parts_mode) {
            ws[bid] = bs;                    // contention-free
        } else {
            atomicAdd(&ws[bid & (NSLOT - 1)], bs);  // fallback: shallow contention
        }
    }
}

// Sum `count4` float4 partials from ws, write 1 - sum/N.
__global__ __launch_bounds__(1024) void ssim_final(const float4* __restrict__ ws4,
                                                   float* __restrict__ out, int count4) {
    __shared__ float red[16];
    const int tid = threadIdx.x;
    float s = 0.f;
    for (int i = tid; i < count4; i += 1024) {
        const float4 w = ws4[i];
        s += (w.x + w.y) + (w.z + w.w);
    }
#pragma unroll
    for (int off = 32; off > 0; off >>= 1) s += __shfl_down(s, off, 64);
    if ((tid & 63) == 0) red[tid >> 6] = s;
    __syncthreads();
    if (tid == 0) {
        float tot = 0.f;
#pragma unroll
        for (int i = 0; i < 16; ++i) tot += red[i];
        out[0] = 1.0f - tot * (1.0f / (float)N_TOT);
    }
}

extern "C" void kernel_launch(void* const* d_in, const int* in_sizes, int n_in,
                              void* d_out, int out_size, void* d_ws, size_t ws_size,
                              hipStream_t stream) {
    const float* pred = (const float*)d_in[0];
    const float* tgt = (const float*)d_in[1];
    float* out = (float*)d_out;
    float* ws = (float*)d_ws;

    const int parts_mode = (ws_size >= (size_t)NBLK * sizeof(float)) ? 1 : 0;
    if (!parts_mode) {
        hipMemsetAsync(ws, 0, NSLOT * sizeof(float), stream);
    }
    dim3 grid(256, 48);  // 16x16 tiles x (16*3) planes
    ssim_main<<<grid, 256, 0, stream>>>(pred, tgt, ws, parts_mode);
    ssim_final<<<1, 1024, 0, stream>>>((const float4*)ws, out,
                                       (parts_mode ? NBLK : NSLOT) / 4);
}

// Round 7
// 160.937 us; speedup vs baseline: 1.8690x; 1.0340x over previous
//
#include <hip/hip_runtime.h>

typedef float f2 __attribute__((ext_vector_type(2)));

#define IMG 512
#define TW 32
#define TH 32
#define NG 12            // float4 col-groups per tile row: 48 cols = 32 out + 8 halo each side
#define SROW 148         // LDS row stride in dwords: 96 A(f2 fp32) + 48 B(packed 2xfp16) + 4 pad
                         //   -> 592 B/row; quad count 37 (ODD: full bank-quad permutation over rows)
#define BOFFD 96         // B-part offset within a row, in dwords (384 B, 16B-aligned)
#define N_TOT (16 * 3 * 512 * 512)
#define NBLK (256 * 48)  // total blocks of ssim_main
#define NSLOT 1024       // fallback atomic slots

// Gaussian(win=11, sigma=1.5), normalized, pre-doubled (SGPR-pair broadcast for pk ops).
__device__ __constant__ f2 Gw2[11] = {
    {0.00102838f, 0.00102838f}, {0.00759876f, 0.00759876f},
    {0.03600077f, 0.03600077f}, {0.10936086f, 0.10936086f},
    {0.21300537f, 0.21300537f}, {0.26601173f, 0.26601173f},
    {0.21300537f, 0.21300537f}, {0.10936086f, 0.10936086f},
    {0.03600077f, 0.03600077f}, {0.00759876f, 0.00759876f},
    {0.00102838f, 0.00102838f}};

// fp16 pack/unpack as pure-u32 inline asm (no _Float16 C-type in this TU).
// Numerics harness-verified absmax 0.0 in rounds 1-6.
__device__ __forceinline__ unsigned pkh(float a, float b) {   // (a,b) -> lo16/hi16 fp16 RTZ
    unsigned r;
    asm("v_cvt_pkrtz_f16_f32 %0, %1, %2" : "=v"(r) : "v"(a), "v"(b));
    return r;
}
__device__ __forceinline__ f2 uph(unsigned u) {               // lo16/hi16 fp16 -> (f32,f32)
    float lo, hi;
    const unsigned uh = u >> 16;
    asm("v_cvt_f32_f16 %0, %1" : "=v"(lo) : "v"(u));
    asm("v_cvt_f32_f16 %0, %1" : "=v"(hi) : "v"(uh));
    return (f2){lo, hi};
}

// Packed vertical taps for a row-pair from one input row k.
__device__ __forceinline__ void vtaps(const float4 P, const float4 T, const int k,
                                      f2 A0[4][2], f2 A1[4][2]) {
    const f2 p[2] = {{P.x, P.y}, {P.z, P.w}};
    const f2 t[2] = {{T.x, T.y}, {T.z, T.w}};
#pragma unroll
    for (int h = 0; h < 2; ++h) {
        const f2 ss = p[h] * p[h] + t[h] * t[h];
        const f2 pt = p[h] * t[h];
        if (k < 11) {                              // tap k for row r0
            const f2 w = Gw2[k];
            A0[0][h] += w * p[h];
            A0[1][h] += w * t[h];
            A0[2][h] += w * ss;
            A0[3][h] += w * pt;
        }
        if (k > 0) {                               // tap k-1 for row r0+1
            const f2 w = Gw2[k - 1];
            A1[0][h] += w * p[h];
            A1[1][h] += w * t[h];
            A1[2][h] += w * ss;
            A1[3][h] += w * pt;
        }
    }
}

// LAUNCH-BOUNDS LAW (7-data-point post-mortem, rounds 0-5 + prev session):
// gfx950 budgets ARCH-VGPRs = 256/min_waves_per_eu (half of the unified 512 file):
//   (256,5)->cap 51 (saw 48, spill)   (256,6)->cap 42 (saw 40, spill)
//   (256,8)+LDS 19456 (8/EU achievable)->cap 32 -> catastrophic spill (rounds 1-5)
//   (256,8)+LDS 26624 (8/EU UNachievable)->constraint dropped -> 60, clean (round 0)
//   (256,4)->cap 64: round 6 measured VGPR 64, WRITE_SIZE 0.4 MB, clean. KEEP AT 4.
// NEVER raise min_waves above 4. NEVER runtime-index register arrays. NEVER
// hand-pipeline the phase-1 k-loop.
// Round-6 lesson: occupancy is NOT LDS-limited (19456 B, 8 blocks/CU legal, still
// ~36% = ~3 blocks resident). The stall is load latency that ~3 waves/SIMD can't hide.
__global__ __launch_bounds__(256, 4) void ssim_main(const float* __restrict__ pred,
                                                    const float* __restrict__ tgt,
                                                    float* __restrict__ ws,
                                                    int parts_mode) {
    // Unified vertically-blurred plane, 32 rows x (48 A-cols fp32 | 48 B-cols packed fp16x2).
    //   A(row,c) = (vblur p, vblur t)              f2  at dword row*SROW + 2c
    //   B(row,c) = pkrtz(vblur p^2+t^2, vblur p*t) u32 at dword row*SROW + BOFFD + c
    // 32*148*4 = 18944 B -> 19456 alloc.
    __shared__ __align__(16) float plane[TH * SROW];
    __shared__ float red[4];

    const int tid = threadIdx.x;
    const int plane_id = blockIdx.y;         // 48 planes

    // XCD-AWARE TILE SWIZZLE (T1): consecutive blockIds round-robin the 8 XCDs, and
    // blockId%8 == blockIdx.x%8 (gridDim.x=256 ≡ 0 mod 8). Linear tile order put
    // halo-sharing neighbor tiles on different XCDs -> halo re-reads miss the per-XCD
    // L2 (FETCH 1.4x ideal, long-latency loads). Remap so each XCD owns a contiguous
    // 32-tile chunk (2 full tile rows) per plane: both horizontal (16x43-col) and
    // vertical (11x48-row) halo reuse become same-XCD L2 hits. Bijective on 0..255.
    const int bx = blockIdx.x;
    const int tile = ((bx & 7) << 5) | (bx >> 3);   // xcd*32 + chunk
    const int tile_x = tile & 15;
    const int tile_y = tile >> 4;
    const int tx = tile_x * TW;
    const int ty = tile_y * TH;
    const float* pbase = pred + (size_t)plane_id * (IMG * IMG);
    const float* tbase = tgt + (size_t)plane_id * (IMG * IMG);

    // ---- Phase 1: vertical 11-tap blur straight from global, row-pair per task ----
    if (tid < NG * 16) {
        const int g4 = tid % NG;             // col group
        const int rp = tid / NG;             // row pair
        const int r0 = rp * 2;               // local output row
        const int col = tx - 8 + (g4 << 2);  // global col of float4 (16B-aligned)
        const int ybase = ty + r0 - 5;

        f2 A0[4][2], A1[4][2];
#pragma unroll
        for (int q = 0; q < 4; ++q)
#pragma unroll
            for (int h = 0; h < 2; ++h) { A0[q][h] = (f2)0.f; A1[q][h] = (f2)0.f; }

        // Block-uniform branch (scalar, no divergence); loads plain, compiler-scheduled.
        if ((unsigned)(tile_x - 1) < 14u && (unsigned)(tile_y - 1) < 14u) {
            const float* pp = pbase + (ybase * IMG + col);
            const float* tp = tbase + (ybase * IMG + col);
#pragma unroll
            for (int k = 0; k < 12; ++k) {
                const float4 P = *(const float4*)(pp + k * IMG);
                const float4 T = *(const float4*)(tp + k * IMG);
                vtaps(P, T, k, A0, A1);
            }
        } else {
            const bool xin = (unsigned)col < (unsigned)IMG;  // all-in or all-out
#pragma unroll
            for (int k = 0; k < 12; ++k) {
                const int y = ybase + k;
                float4 P = make_float4(0.f, 0.f, 0.f, 0.f);
                float4 T = make_float4(0.f, 0.f, 0.f, 0.f);
                if (xin && (unsigned)y < (unsigned)IMG) {
                    const int gidx = y * IMG + col;
                    P = *(const float4*)(pbase + gidx);
                    T = *(const float4*)(tbase + gidx);
                }
                vtaps(P, T, k, A0, A1);
            }
        }

        // Transpose in registers -> b128 stores. r is a compile-time unroll var.
        const int cb = g4 << 2;              // pixel col base (col 0 == global tx-8)
#pragma unroll
        for (int r = 0; r < 2; ++r) {
            f2 (*A)[2] = r ? A1 : A0;
            float* rowA = &plane[(r0 + r) * SROW + (cb << 1)];
            *(float4*)rowA       = make_float4(A[0][0].x, A[1][0].x, A[0][0].y, A[1][0].y);
            *(float4*)(rowA + 4) = make_float4(A[0][1].x, A[1][1].x, A[0][1].y, A[1][1].y);
            // B: 4 pixels packed fp16x2(ss,pt) = one uint4 = one ds_write_b128.
            uint4 bv;
            bv.x = pkh(A[2][0].x, A[3][0].x);
            bv.y = pkh(A[2][0].y, A[3][0].y);
            bv.z = pkh(A[2][1].x, A[3][1].x);
            bv.w = pkh(A[2][1].y, A[3][1].y);
            *(uint4*)&plane[(r0 + r) * SROW + BOFFD + cb] = bv;
        }
    }
    __syncthreads();

    // ---- Phase 2: packed horizontal 11-tap blur + SSIM map, 4 outputs per thread ----
    // SCATTER form: each loaded pixel is consumed immediately into the <=4 outputs it
    // feeds. Peak live ~30 dwords.
    float lsum = 0.f;
    {
        const int oy = tid >> 3;             // 32 rows
        const int ox = (tid & 7) << 2;       // 8 groups of 4 output cols
        const float* rowbase = &plane[oy * SROW];

        f2 acc[4];                           // (mu1, mu2) per j
        f2 sacc[4];                          // (bss, bpt) per j
#pragma unroll
        for (int j = 0; j < 4; ++j) { acc[j] = (f2)0.f; sacc[j] = (f2)0.f; }

        // A part: load f2 cols ox+2..ox+17 (8 x b128, 16B-aligned). Pixel index i
        // (col ox+2+i) feeds output j with weight Gw2[i-1-j] when 0<=i-1-j<=10.
        {
            const float4* rowA = (const float4*)(rowbase + ((ox + 2) << 1));
#pragma unroll
            for (int i4 = 0; i4 < 8; ++i4) {
                const float4 q = rowA[i4];
                const f2 v[2] = {{q.x, q.y}, {q.z, q.w}};
#pragma unroll
                for (int h = 0; h < 2; ++h) {
                    const int i = 2 * i4 + h;
#pragma unroll
                    for (int j = 0; j < 4; ++j) {
                        const int k = i - 1 - j;
                        if (k >= 0 && k <= 10) acc[j] += Gw2[k] * v[h];
                    }
                }
            }
        }

        // B part: load packed pixels ox..ox+19 (5 x b128, contiguous span). Pixel
        // offset m (col ox+m) feeds output j with weight Gw2[m-3-j] when 0<=m-3-j<=10.
        {
            const uint4* rowB = (const uint4*)(rowbase + BOFFD + ox);
#pragma unroll
            for (int i4 = 0; i4 < 5; ++i4) {
                const uint4 q = rowB[i4];
                const unsigned qq[4] = {q.x, q.y, q.z, q.w};
#pragma unroll
                for (int c = 0; c < 4; ++c) {
                    const int m = 4 * i4 + c;
                    if (m >= 3 && m <= 16) {
                        const f2 v = uph(qq[c]);
#pragma unroll
                        for (int j = 0; j < 4; ++j) {
                            const int k = m - 3 - j;
                            if (k >= 0 && k <= 10) sacc[j] += Gw2[k] * v;
                        }
                    }
                }
            }
        }

        const float C1 = 0.0001f;            // 0.01^2
        const float C2 = 0.0009f;            // 0.03^2
#pragma unroll
        for (int j = 0; j < 4; ++j) {
            const float m1 = acc[j].x, m2 = acc[j].y;
            const float bss = sacc[j].x, bpt = sacc[j].y;
            const float mu1s = m1 * m1;
            const float mu2s = m2 * m2;
            const float mu12 = m1 * m2;
            const float A = mu1s + mu2s;
            const float s12 = bpt - mu12;    // sigma12
            const float sden = bss - A;      // sigma1^2 + sigma2^2
            const float num = fmaf(2.f, mu12, C1) * fmaf(2.f, s12, C2);
            const float den = (A + C1) * (sden + C2);
            lsum += num * __builtin_amdgcn_rcpf(den);   // rcp err ~1e-7 << 1.98e-2 threshold
        }
    }

    // ---- Reduction: wave shuffle -> LDS -> one plain store per block ----
#pragma unroll
    for (int off = 32; off > 0; off >>= 1) lsum += __shfl_down(lsum, off, 64);
    if ((tid & 63) == 0) red[tid >> 6] = lsum;
    __syncthreads();
    if (tid == 0) {
        const float bs = (red[0] + red[1]) + (red[2] + red[3]);
        const int bid = blockIdx.y * gridDim.x + blockIdx.x;
        if (parts_mode) {
            ws[bid] = bs;                    // contention-free
        } else {
            atomicAdd(&ws[bid & (NSLOT - 1)], bs);  // fallback: shallow contention
        }
    }
}

// Sum `count4` float4 partials from ws, write 1 - sum/N.
__global__ __launch_bounds__(1024) void ssim_final(const float4* __restrict__ ws4,
                                                   float* __restrict__ out, int count4) {
    __shared__ float red[16];
    const int tid = threadIdx.x;
    float s = 0.f;
    for (int i = tid; i < count4; i += 1024) {
        const float4 w = ws4[i];
        s += (w.x + w.y) + (w.z + w.w);
    }
#pragma unroll
    for (int off = 32; off > 0; off >>= 1) s += __shfl_down(s, off, 64);
    if ((tid & 63) == 0) red[tid >> 6] = s;
    __syncthreads();
    if (tid == 0) {
        float tot = 0.f;
#pragma unroll
        for (int i = 0; i < 16; ++i) tot += red[i];
        out[0] = 1.0f - tot * (1.0f / (float)N_TOT);
    }
}

extern "C" void kernel_launch(void* const* d_in, const int* in_sizes, int n_in,
                              void* d_out, int out_size, void* d_ws, size_t ws_size,
                              hipStream_t stream) {
    const float* pred = (const float*)d_in[0];
    const float* tgt = (const float*)d_in[1];
    float* out = (float*)d_out;
    float* ws = (float*)d_ws;

    const int parts_mode = (ws_size >= (size_t)NBLK * sizeof(float)) ? 1 : 0;
    if (!parts_mode) {
        hipMemsetAsync(ws, 0, NSLOT * sizeof(float), stream);
    }
    dim3 grid(256, 48);  // 16x16 tiles x (16*3) planes
    ssim_main<<<grid, 256, 0, stream>>>(pred, tgt, ws, parts_mode);
    ssim_final<<<1, 1024, 0, stream>>>((const float4*)ws, out,
                                       (parts_mode ? NBLK : NSLOT) / 4);
}